// Round 10
// baseline (269.315 us; speedup 1.0000x reference)
//
#include <hip/hip_runtime.h>

// BERTEmbedding: out[p, 0:256]   = x[p,0:10] @ W^T + b       (fp32)
//                out[p, 256:512] = sinusoidal PE row doy[p]  (fp32)
// p over B*S = 131072 positions, all fp32.
//
// r13 == r8 resubmitted (rounds 5-9 all failed with GPUAcquisitionTimeout;
// no measurement taken). r8 == r6 + compile fix (__builtin_nontemporal_store
// needs a clang native vector type -> ext_vector_type, not HIP float4).
//
// r6: r5 kernel ~98 us vs 43 us write floor. Issue-rate model says VALU is
// 5x over what HBM needs, so the residual is latency serialization:
// per-iter dependent ds_read broadcasts (~120 cyc) + only 4 waves/SIMD to
// hide them + 640 scattered L1 line transactions per wave for W. Fixes:
//  - CHUNK 32->16 (2048 blocks): up to ~24 waves/CU for latency hiding
//  - explicit software pipeline: prefetch next x-row/doy into regs before
//    computing current iteration (ds latency hides under FMA+trans)
//  - W^T staged coalesced into LDS once/block; lanes read their 40-float
//    slice via 10 conflict-free ds_read_b128 (no scattered global W)
//  - nontemporal stores (write-once output, skip L2 allocate)

#define CHUNK  16    // positions per wave
#define BLKPOS 64    // positions per block (4 waves)

typedef float f32x4 __attribute__((ext_vector_type(4)));

__global__ __launch_bounds__(256) void bert_embed_kernel(
    const float* __restrict__ x,      // [BS, 10]  fp32
    const int*   __restrict__ doy,    // [BS]      int32
    const float* __restrict__ W,      // [256, 10] fp32
    const float* __restrict__ bvec,   // [256]     fp32
    float*       __restrict__ out,    // [BS, 512] fp32
    int BS)
{
    __shared__ float lwt[10 * 256];    // 10 KB: W^T, lwt[f*256+d] = W[d,f]
    __shared__ float lx[BLKPOS * 10];  // 2.5 KB: x rows for this block
    __shared__ float ldoyf[BLKPOS];    // 256 B: doy as float

    const int tid  = threadIdx.x;
    const int lane = tid & 63;
    const int wave = tid >> 6;
    const int blk_base = blockIdx.x * BLKPOS;
    if (blk_base >= BS) return;
    const int valid = min(BLKPOS, BS - blk_base);

    // --- stage W^T: thread t reads W row t (10 floats), writes column t.
    //     ds_write stride-256 across tids -> consecutive addrs, conflict-free.
    {
        const float* wr = W + (size_t)tid * 10;
        #pragma unroll
        for (int f = 0; f < 10; ++f) lwt[f * 256 + tid] = wr[f];
    }
    // --- stage x block: 640 floats = 160 float4, coalesced ---
    if (valid == BLKPOS) {
        const f32x4* xb = (const f32x4*)(x + (size_t)blk_base * 10); // blk_base*40B, 16B-aligned
        if (tid < 160) ((f32x4*)lx)[tid] = xb[tid];
    } else {
        for (int i = tid; i < valid * 10; i += 256)
            lx[i] = x[(size_t)blk_base * 10 + i];
    }
    if (tid < valid) ldoyf[tid] = (float)doy[blk_base + tid];

    const int d0 = lane * 4;
    const f32x4 bv = *(const f32x4*)(bvec + d0);

    // PE frequency factors (position-independent):
    // rev = pos * 2^(-j*log2(1e4)/128 - log2(2*pi)),  pe = sin/cos(2*pi*rev)
    const float e0 = __builtin_amdgcn_exp2f(
        fmaf((float)(2 * lane + 0), -0.10381025296522976f, -2.651496129472319f));
    const float e1 = __builtin_amdgcn_exp2f(
        fmaf((float)(2 * lane + 1), -0.10381025296522976f, -2.651496129472319f));

    __syncthreads();

    // --- per-lane W slice from LDS: 10 conflict-free ds_read_b128 ---
    float wf[40];
    #pragma unroll
    for (int f = 0; f < 10; ++f) {
        f32x4 v = *(const f32x4*)(lwt + f * 256 + d0);
        wf[ 0 + f] = v.x;   // row d0+0, feature f
        wf[10 + f] = v.y;   // row d0+1
        wf[20 + f] = v.z;   // row d0+2
        wf[30 + f] = v.w;   // row d0+3
    }

    const int wbase = wave * CHUNK;
    const int n = min(CHUNK, valid - wbase);
    if (n <= 0) return;
    float* o = out + ((size_t)blk_base + wbase) * 512 + d0;

    // --- software pipeline: prefetch row it+1 while computing row it ---
    float xf[10]; float posv;
    {
        const float* xr = lx + wbase * 10;
        #pragma unroll
        for (int c = 0; c < 5; ++c) {
            float2 v = *(const float2*)(xr + 2 * c);
            xf[2 * c] = v.x; xf[2 * c + 1] = v.y;
        }
        posv = ldoyf[wbase];
    }

    for (int it = 0; it < n; ++it) {
        float xn[10]; float posn = 0.0f;
        if (it + 1 < n) {
            const float* xr = lx + (wbase + it + 1) * 10;
            #pragma unroll
            for (int c = 0; c < 5; ++c) {
                float2 v = *(const float2*)(xr + 2 * c);
                xn[2 * c] = v.x; xn[2 * c + 1] = v.y;
            }
            posn = ldoyf[wbase + it + 1];
        }

        // obs_embed: 4 output dims per lane, K=10
        float acc0 = bv.x, acc1 = bv.y, acc2 = bv.z, acc3 = bv.w;
        #pragma unroll
        for (int f = 0; f < 10; ++f) {
            acc0 = fmaf(xf[f], wf[ 0 + f], acc0);
            acc1 = fmaf(xf[f], wf[10 + f], acc1);
            acc2 = fmaf(xf[f], wf[20 + f], acc2);
            acc3 = fmaf(xf[f], wf[30 + f], acc3);
        }

        // PE
        float r0 = posv * e0;
        float r1 = posv * e1;
        r0 -= floorf(r0);                       // [0,1) revolutions
        r1 -= floorf(r1);
        f32x4 s1 = { __builtin_amdgcn_sinf(r0), __builtin_amdgcn_cosf(r0),
                     __builtin_amdgcn_sinf(r1), __builtin_amdgcn_cosf(r1) };
        f32x4 s0 = { acc0, acc1, acc2, acc3 };

        // write-once output: nontemporal, contiguous 2 KB per position
        __builtin_nontemporal_store(s0, (f32x4*)(o));
        __builtin_nontemporal_store(s1, (f32x4*)(o + 256));
        o += 512;

        if (it + 1 < n) {
            #pragma unroll
            for (int k = 0; k < 10; ++k) xf[k] = xn[k];
            posv = posn;
        }
    }
}

extern "C" void kernel_launch(void* const* d_in, const int* in_sizes, int n_in,
                              void* d_out, int out_size, void* d_ws, size_t ws_size,
                              hipStream_t stream) {
    const float* x    = (const float*)d_in[0];
    const int*   doy  = (const int*)d_in[1];
    const float* W    = (const float*)d_in[2];
    const float* bvec = (const float*)d_in[3];
    float*       out  = (float*)d_out;

    const int BS = in_sizes[1];                         // B*S = 131072 positions
    const int blocks = (BS + BLKPOS - 1) / BLKPOS;      // 64 positions per block
    bert_embed_kernel<<<blocks, 256, 0, stream>>>(x, doy, W, bvec, out, BS);
}